// Round 9
// baseline (145.885 us; speedup 1.0000x reference)
//
#include <hip/hip_runtime.h>

// Problem constants (fixed in the reference file)
#define OHh   60
#define OWw   60
#define NBINS (OHh * OWw)   // 3600
#define NB    64            // batches
#define NS    4096          // spikes per batch
#define CAP   128

#define NW     4            // waves per block
#define RPB    2            // rows per block (6-row halo band, one scan)
#define RG     (OHh / RPB)  // 30 row-groups
#define SEG    (NS / NW)    // 1024 spikes scanned per wave
#define CH     (SEG / 64)   // 16 chunks per wave
#define HCAP   160          // hit cap per wave (lambda ~96 for 6-row band;
                            //  P(>160) ~ 2e-8/wave -> ovf fallback)
#define HBUF   176          // hitbuf entries (sink region [160,176))
#define PW     5            // presence words per (wave,row,bin): 160 bits
#define PRE0   64           // slots [PRE0, CAP) prefilled -1 during scan
                            // (per-bin row total ~ Poisson(25); P(>64) ~ 1e-11)

// One 4-wave block per (batch, ROW PAIR); lane == ow (lanes 60..63 parked).
// R16: R15 (hit-parallel presence scatter) won as predicted; issue is now
// ~50% with phase 1 (16-chunk spike decode, 40% of issue) re-scanning the
// batch's 4096 spikes once per row (60x redundancy). R16 serves TWO rows
// per block from ONE scan: phase 1 tests a 6-row band (kh6 = h-row0 in
// [0,6)) and stores R=(kh6<<16)|(w<<10)|A once; phase 2's 12x5 hit-lanes
// set presence bits for both rows from the same record (row j valid iff
// kh6-j in [0,5)); phases 3/4 run per row, reusing one outimg (re-init
// fused into phase-4 row 0). Per-row phase-1 cost halves, per-row spike
// fetch halves, grid halves to 1920 -> ~single-round residency at
// 7 blocks/CU (LDS 22.8 KB). s-order per row: wave prefix x (chunk, lane)
// order, reconstructed by ascending presence-bit index (= s order).
__global__ __launch_bounds__(256) void sort_spikes_pair(
    const int* __restrict__ spikes, int* __restrict__ out) {
    const int bid  = (int)blockIdx.x;
    const int b    = bid & (NB - 1);   // batch-minor -> batch b pinned to XCD b%8
    const int rg   = bid >> 6;         // row-group 0..29
    const int tid  = (int)threadIdx.x;
    const int wv   = tid >> 6;
    const int lane = tid & 63;
    const bool valid = lane < OWw;
    const int row0 = rg * RPB;         // rows row0, row0+1

    __shared__ int            hitbuf[NW][HBUF];      // 2816 B (packed records)
    __shared__ unsigned       pres[NW][RPB][64][PW]; // 10240 B; stride 5 dwords
                                                     //  coprime 32 -> bank-free
    __shared__ unsigned short outimg[PRE0][OWw];     // 7680 B [k][ow], reused/row
    __shared__ int            cnt[NW][RPB][64];      // 2048 B
    __shared__ int            ovf;                   // 22788 B -> 7 blocks/CU

    if (tid == 0) ovf = 0;
#pragma unroll
    for (int i = 0; i < PW; ++i) {     // zero own-wave presence, both rows
        pres[wv][0][lane][i] = 0u;
        pres[wv][1][lane][i] = 0u;
    }
    {   // outimg := all 0xFFFF (-1); 1920 dwords across 256 threads
        int* oi = (int*)&outimg[0][0];
        for (int i = tid; i < PRE0 * OWw / 2; i += 256) oi[i] = -1;
    }

    const int* __restrict__ sp = spikes + b * NS + wv * SEG;
    int* __restrict__ outb0 = out + (size_t)b * (CAP * NBINS) + row0 * OWw;
    int* __restrict__ outb1 = outb0 + OWw;

    // Issue all 16 chunk loads up front (deep vmcnt pipeline; L2-resident
    // after the first of a batch's 30 blocks touches them).
    int vs[CH];
#pragma unroll
    for (int c = 0; c < CH; ++c) vs[c] = sp[c * 64 + lane];

    int* const hb_w = &hitbuf[wv][0];

    // ---- Phase 1: ONE scan collects the 6-row band, s-ordered. ----
    // R = (kh6<<16)|(w<<10)|A with A = c*25 + kh6*5 + w in [0,864) for halo.
    int hbase = 0;
#pragma unroll
    for (int c = 0; c < CH; ++c) {
        const int v   = vs[c];
        const int h   = (v >> 6) & 63;
        const int kh6 = h - row0;
        const bool halo = (unsigned)kh6 < 6u;
        const int w   = v & 63;
        const int A   = (v >> 12) * 25 + kh6 * 5 + w;
        const int R   = (kh6 << 16) | (w << 10) | A;

        const unsigned long long mask = __ballot(halo);   // wave-uniform
        const int pos = __builtin_amdgcn_mbcnt_hi(
            (unsigned)(mask >> 32),
            __builtin_amdgcn_mbcnt_lo((unsigned)mask, 0));
        if (halo) hb_w[min(hbase + pos, HBUF - 1)] = R;   // s-order preserved
        hbase += (int)__popcll(mask);                     // uniform

        // Hidden prefill: one -1 slot-row per chunk per row -> both rows'
        // slots [64,128) done by scan end. Contiguous 240 B runs, paced.
        if (valid) {
            const int so = (PRE0 + wv * CH + c) * NBINS + lane;
            outb0[so] = -1;
            outb1[so] = -1;
        }
    }
    if (hbase > HCAP && lane == 0) ovf = 1;   // truncated list (P ~ 2e-8/wave)
    const int n = min(hbase, HCAP);           // wave-uniform

    // ---- Phase 2: hit-parallel presence scatter, 12 hits x 5 kw-lanes,
    //      BOTH rows from one record read. ----
    const int qi  = (lane < OWw) ? (lane / 5) : 4096;  // parked: hidx>=n always
    const int kwc = lane - qi * 5;
    for (int hbi = 0; hbi < n; hbi += 12) {            // uniform trip (~8 iters)
        const int hidx = hbi + qi;
        const int R    = hb_w[min(hidx, HBUF - 1)];    // 5-lane shared-addr read
        const int w    = (R >> 10) & 63;
        const int kh6  = R >> 16;
        const int bin  = w - kwc;                      // this lane's candidate ow
        const bool vb  = ((unsigned)bin < 60u) & (hidx < n);
        const unsigned bit = 1u << (hidx & 31);
        const int word = hidx >> 5;
        if (vb & ((unsigned)kh6 < 5u))                 // row 0: kh6 in [0,5)
            atomicOr(&pres[wv][0][bin][word], bit);
        if (vb & ((unsigned)(kh6 - 1) < 5u))           // row 1: kh6 in [1,6)
            atomicOr(&pres[wv][1][bin][word], bit);
    }

    // Own-bin masks + counts (atomics above are same-wave -> DS-pipe order).
    unsigned mw[RPB][PW];
#pragma unroll
    for (int j = 0; j < RPB; ++j) {
        unsigned s = 0;
#pragma unroll
        for (int i = 0; i < PW; ++i) {
            mw[j][i] = pres[wv][j][lane][i];
            s += __builtin_popcount(mw[j][i]);
        }
        cnt[wv][j][lane] = (int)s;
    }
    __syncthreads();

    if (ovf == 0) {
#pragma unroll
        for (int j = 0; j < RPB; ++j) {
            int* __restrict__ outbj = (j == 0) ? outb0 : outb1;
            // ---- Phase 3 (row j): lane = bin; iterate own wave's mask
            //      ascending (= s-order), scatter ck into outimg at
            //      k = cross-wave prefix + rank. ----
            if (valid) {
                int k = 0;
                for (int wq = 0; wq < wv; ++wq) k += cnt[wq][j][lane];
                const int sub = lane + 5 * j;          // ck = A - 5j - bin
#pragma unroll
                for (int wd = 0; wd < PW; ++wd) {
                    unsigned mm = mw[j][wd];
                    while (mm) {                       // divergent; wall = max cnt
                        const int t = __builtin_ctz(mm);
                        mm &= mm - 1;
                        const int src = wd * 32 + t;
                        const int ck  = (hb_w[src] & 0x3ff) - sub;
                        if (k < PRE0) outimg[k][lane] = (unsigned short)ck;
                        else if (k < CAP) outbj[k * NBINS + lane] = ck; // ~1e-11
                        ++k;
                    }
                }
            }
            __syncthreads();
            // ---- Phase 4 (row j): stream outimg -> global, 16 rows/wave,
            //      proven contiguous-240B pattern; fused -1 re-init (row 0). ----
            if (valid) {
#pragma unroll 4
                for (int i = 0; i < PRE0 / NW; ++i) {
                    const int kk  = wv * (PRE0 / NW) + i;
                    const int val = (int)(short)outimg[kk][lane];
                    if (j == 0) outimg[kk][lane] = 0xFFFFu;  // re-init for row 1
                    outbj[kk * NBINS + lane] = val;
                }
            }
            if (j == 0) __syncthreads();   // row-1 phase 3 needs clean outimg
        }
    } else if (wv < RPB) {
        // Fallback (P ~ 3e-4/launch): waves 0,1 each redo one row serially
        // over all 4096 spikes, direct global stores (overwrites prefill).
        const int rowf = row0 + wv;
        int* __restrict__ outbf = (wv == 0) ? outb0 : outb1;
        const int* __restrict__ spf = spikes + b * NS;
        int cc = 0;
        for (int c = 0; c < NS / 64; ++c) {
            const int v = spf[c * 64 + lane];
            const int h = (v >> 6) & 63;
            unsigned long long mask = __ballot((unsigned)(h - rowf) < 5u);
            while (mask) {
                const int j = (int)__builtin_ctzll(mask);
                mask &= mask - 1;
                const int vj =
                    __builtin_amdgcn_readlane(v, __builtin_amdgcn_readfirstlane(j));
                const int wj  = vj & 63;
                const int khj = ((vj >> 6) & 63) - rowf;
                const int cj  = vj >> 12;
                const int kw  = wj - lane;
                if (((unsigned)kw < 5u) & valid) {
                    if (cc < CAP)
                        outbf[cc * NBINS + lane] = cj * 25 + khj * 5 + kw;
                    ++cc;
                }
            }
        }
        if (valid)
            for (int k = cc; k < CAP; ++k) outbf[k * NBINS + lane] = -1;
    }
}

extern "C" void kernel_launch(void* const* d_in, const int* in_sizes, int n_in,
                              void* d_out, int out_size, void* d_ws, size_t ws_size,
                              hipStream_t stream) {
    const int* spikes = (const int*)d_in[0];  // (B, S, 1, 1) int32
    // d_in[1] (indices table) unused: membership is pure arithmetic.
    int* out = (int*)d_out;                   // (B, CAP, OH, OW) int32

    dim3 grid(RG * NB);                       // 1920 blocks, batch-minor
    dim3 block(256);                          // 4 waves/block
    sort_spikes_pair<<<grid, block, 0, stream>>>(spikes, out);
}

// Round 10
// 138.617 us; speedup vs baseline: 1.0524x; 1.0524x over previous
//
#include <hip/hip_runtime.h>

// Problem constants (fixed in the reference file)
#define OHh   60
#define OWw   60
#define NBINS (OHh * OWw)   // 3600
#define NB    64            // batches
#define NS    4096          // spikes per batch
#define CAP   128

#define NW     4            // waves per block
#define SEG    (NS / NW)    // 1024 spikes scanned per wave
#define CH     (SEG / 64)   // 16 chunks per wave
#define HCAP   160          // hit-list cap per wave (lambda ~80, +9 sigma)
#define HBUF   176          // hitbuf entries: [0,160) hits, [n,n+12) sentinels
#define PW     5            // presence words per (wave,bin): 160 bits
#define PRE0   64           // slots [PRE0, CAP) prefilled -1 during scan
                            // (per-bin total ~ Poisson(25); P(>64) ~ 1e-11)

// One 4-wave block per (batch, output row); lane == ow. R17 = R15 (best
// measured: 138.1 us; hit-parallel presence scatter) + span-neutral issue
// trims. R16's row-pair amortization regressed (+7.8 us): phase-3/4
// serialization + 3 barriers + doubled scan stores cost more than the
// phase-1 savings -- span beats issue in this kernel. R17 trims issue only:
//  (1) sentinel-padded hit list (12x R=64<<16 at [n,n+12)): phase 2 loses
//      the hidx<n test and min() clamp; parked lanes become group qi=12
//      whose atomicOr bits duplicate the next iteration's groups exactly
//      (same record/bin/bit -> idempotent) -- no special case.
//  (2) -row5 folded out of the 16x chunk decode into phase 3's constant.
//  (3) spike loads issued before LDS init (latency overlaps zeroing).
//  (4) pres stride 7->5 dwords (coprime 32, bank-free): LDS 16.6 KB.
__global__ __launch_bounds__(256) void sort_spikes_row4(
    const int* __restrict__ spikes, int* __restrict__ out) {
    const int bid  = (int)blockIdx.x;
    const int b    = bid & (NB - 1);   // batch-minor -> batch b pinned to XCD b%8
    const int row  = bid >> 6;         // output row oh, 0..59
    const int tid  = (int)threadIdx.x;
    const int wv   = tid >> 6;
    const int lane = tid & 63;
    const bool valid = lane < OWw;

    __shared__ int            hitbuf[NW][HBUF];   // 2816 B (u32 hit records)
    __shared__ unsigned       pres[NW][64][PW];   // 5120 B; stride 5 coprime 32
    __shared__ unsigned short outimg[PRE0][OWw];  // 7680 B [k][ow] staging image
    __shared__ int            cnt[NW][64];        // 1024 B
    __shared__ int            ovf;                // total ~16.6 KB -> 8 blocks/CU

    const int* __restrict__ sp   = spikes + b * NS + wv * SEG;
    int* __restrict__       outb = out + (size_t)b * (CAP * NBINS) + row * OWw;

    // Issue all 16 chunk loads FIRST (deep vmcnt pipeline; latency overlaps
    // the LDS zeroing below; L2-resident after a batch's first block).
    int vs[CH];
#pragma unroll
    for (int c = 0; c < CH; ++c) vs[c] = sp[c * 64 + lane];

    if (tid == 0) ovf = 0;
#pragma unroll
    for (int i = 0; i < PW; ++i) pres[wv][lane][i] = 0u;  // own-wave region only
    {   // outimg := all 0xFFFF (-1 rows); 1920 dwords across 256 threads
        int* oi = (int*)&outimg[0][0];
        for (int i = tid; i < PRE0 * OWw / 2; i += 256) oi[i] = -1;
    }

    int* const hb_w = &hitbuf[wv][0];

    // ---- Phase 1: collect this wave's halo hits, s-ordered, as u32 records
    //      R = (w<<16) | A with A = c*25 + h*5 + w  (ck = A - 5*row - bin). ----
    int hbase = 0;
#pragma unroll
    for (int c = 0; c < CH; ++c) {
        const int v = vs[c];
        const int h = (v >> 6) & 63;
        const int w = v & 63;
        const int A = (v >> 12) * 25 + h * 5 + w;   // <= 1153, fits low half
        const int R = (w << 16) | A;
        const bool halo = (unsigned)(h - row) < 5u;

        const unsigned long long mask = __ballot(halo);   // wave-uniform
        const int pos = __builtin_amdgcn_mbcnt_hi(
            (unsigned)(mask >> 32),
            __builtin_amdgcn_mbcnt_lo((unsigned)mask, 0));
        if (halo) hb_w[min(hbase + pos, HCAP - 1)] = R;   // s-order preserved
        hbase += (int)__popcll(mask);                     // uniform

        // Hidden write: one -1 slot-row per chunk -> slots [64,128) done by
        // scan end (wv*CH+c spans 0..63). Contiguous 240 B run, paced.
        if (valid) outb[(PRE0 + wv * CH + c) * NBINS + lane] = -1;
    }
    if (hbase > HCAP && lane == 0) ovf = 1;   // truncated list (P ~ 1e-50)
    const int n = min(hbase, HCAP);           // wave-uniform
    // Sentinels: bin = 64-kwc >= 60 for every kw lane -> self-disabling.
    if (lane < 12) hb_w[n + lane] = 64 << 16; // [n, n+12) <= [160,172) < HBUF

    // ---- Phase 2: hit-parallel presence scatter, 12 hits x 5 kw-lanes.
    //      Lanes 60..63 form group 12 duplicating the next iteration's
    //      groups bit-for-bit (idempotent atomicOr) -- no parked case. ----
    const int qi  = lane / 5;                 // 0..12
    const int kwc = lane - qi * 5;            // 0..4
    for (int hbi = 0; hbi < n; hbi += 12) {   // uniform trip (~7 iters)
        const int hidx = hbi + qi;            // <= 156+12 = 168 < HBUF
        const int R    = hb_w[hidx];          // 5-lane shared-addr read
        const int bin  = (R >> 16) - kwc;     // this lane's candidate ow
        if ((unsigned)bin < 60u)              // sentinels/overhang drop out here
            atomicOr(&pres[wv][bin][hidx >> 5], 1u << (hidx & 31));
    }

    // Own-bin count (atomics above are same-wave -> DS-pipe program order).
    unsigned m0 = pres[wv][lane][0], m1 = pres[wv][lane][1];
    unsigned m2 = pres[wv][lane][2], m3 = pres[wv][lane][3];
    unsigned m4 = pres[wv][lane][4];
    cnt[wv][lane] = __builtin_popcount(m0) + __builtin_popcount(m1) +
                    __builtin_popcount(m2) + __builtin_popcount(m3) +
                    __builtin_popcount(m4);
    __syncthreads();

    if (ovf == 0) {
        // ---- Phase 3: order reconstruction. lane = bin; iterate own wave's
        //      mask ascending (= s-order), scatter ck into outimg at
        //      k = cross-wave prefix + rank. ----
        if (valid) {
            int k = 0;
            for (int w = 0; w < wv; ++w) k += cnt[w][lane];  // cross-wave prefix
            const int sub = row * 5 + lane;   // ck = A - 5*row - bin
            unsigned mw[PW] = {m0, m1, m2, m3, m4};
#pragma unroll
            for (int wd = 0; wd < PW; ++wd) {
                unsigned mm = mw[wd];
                while (mm) {                       // divergent; wall = max count
                    const int j = __builtin_ctz(mm);
                    mm &= mm - 1;
                    const int src = wd * 32 + j;
                    const int ck  = (hb_w[src] & 0xffff) - sub;  // ckk gather
                    if (k < PRE0) outimg[k][lane] = (unsigned short)ck;
                    else if (k < CAP) outb[k * NBINS + lane] = ck;  // P ~ 1e-11
                    ++k;
                }
            }
        }
        __syncthreads();
        // ---- Phase 4: stream outimg -> global, 16 rows per wave, the proven
        //      contiguous-240B-run pattern (k-major, lane = ow). ----
        if (valid) {
#pragma unroll 4
            for (int i = 0; i < PRE0 / NW; ++i) {
                const int kk = wv * (PRE0 / NW) + i;
                outb[kk * NBINS + lane] = (int)(short)outimg[kk][lane];
            }
        }
    } else if (wv == 0) {
        // Fallback (P ~ 1e-50): serial redo, direct global stores.
        const int* __restrict__ spf = spikes + b * NS;
        int cc = 0;
        for (int c = 0; c < NS / 64; ++c) {
            const int v = spf[c * 64 + lane];
            const int h = (v >> 6) & 63;
            unsigned long long mask = __ballot((unsigned)(h - row) < 5u);
            while (mask) {
                const int j = (int)__builtin_ctzll(mask);
                mask &= mask - 1;
                const int vj =
                    __builtin_amdgcn_readlane(v, __builtin_amdgcn_readfirstlane(j));
                const int wj  = vj & 63;
                const int khj = ((vj >> 6) & 63) - row;
                const int cj  = vj >> 12;
                const int kw  = wj - lane;
                if (((unsigned)kw < 5u) & valid) {
                    if (cc < CAP)
                        outb[cc * NBINS + lane] = cj * 25 + khj * 5 + kw;
                    ++cc;
                }
            }
        }
        if (valid)
            for (int k = cc; k < CAP; ++k) outb[k * NBINS + lane] = -1;
    }
}

extern "C" void kernel_launch(void* const* d_in, const int* in_sizes, int n_in,
                              void* d_out, int out_size, void* d_ws, size_t ws_size,
                              hipStream_t stream) {
    const int* spikes = (const int*)d_in[0];  // (B, S, 1, 1) int32
    // d_in[1] (indices table) unused: membership is pure arithmetic.
    int* out = (int*)d_out;                   // (B, CAP, OH, OW) int32

    dim3 grid(OHh * NB);                      // 3840 blocks, batch-minor
    dim3 block(256);                          // 4 waves/block
    sort_spikes_row4<<<grid, block, 0, stream>>>(spikes, out);
}